// Round 16
// baseline (55.657 us; speedup 1.0000x reference)
//
#include <hip/hip_runtime.h>

// MaxChamferDistance: x[16,4096,3], y[16,4096,3] f32 -> scalar f32
//
// Round-16: mm pinned ~24us across 5 structural knobs => attack the ~6-8us
// OUTSIDE mm: combine kernel (2MB cross-XCD slab read), graph drain, slab
// writes. Each block is now self-sufficient:
//  - 1024 blocks x 256 thr (4 blocks/CU, 4 waves): block = (db, 128 own pts).
//    Loops ALL 4096 other pts via 4 LDS stages (32KB, 2 barriers/stage)
//    -> block-local COMPLETE min -> one partial sum. No gm slab, no combine.
//  - per wave: NT=1 n-tile; 128 A-tiles x [ds_read_b128 + MFMA 32x32x16 +
//    8 v_min3 into rm[8]] (pairwise running mins; tree once in epilogue).
//  - last block (device counter, r6/r8-proven) folds partials[1024] ->
//    mean/max/mean -> out, all fixed-order => replay-deterministic.
//  - launches: memset(cnt) + mm. Numerics r12-verbatim (absmax 0 x6):
//    A=[ybh(3),ybl(3),ybh(3),wh,wl], B=[xh(3),xh(3),xl(3),1,1],
//    exact-f32 ||x||^2 post-min.

typedef __attribute__((ext_vector_type(8)))  short bf16x8;
typedef __attribute__((ext_vector_type(16))) float f32x16;

#define BATCH   16
#define NPTS    4096
#define DB      (2 * BATCH)            // 32 (dir,batch)
#define TPB     256                    // 4 waves
#define CHUNK   128                    // own pts per block (4 n-tiles)
#define NBLK    (DB * (NPTS / CHUNK))  // 1024
#define NSTAGE  4                      // other-cloud stages of 1024 pts

static __device__ __forceinline__ unsigned bf16rn(float f) {
  unsigned u = __float_as_uint(f);
  return (u + 0x7FFFu + ((u >> 16) & 1u)) >> 16;   // round-to-nearest-even
}
static __device__ __forceinline__ float bf2f(unsigned h) {
  return __uint_as_float(h << 16);
}
static __device__ __forceinline__ unsigned pk(unsigned lo, unsigned hi) {
  return (lo & 0xFFFFu) | (hi << 16);
}

__global__ __launch_bounds__(TPB, 4) void chamfer_mm(
    const float* __restrict__ x, const float* __restrict__ y,
    float* __restrict__ partials, unsigned* __restrict__ cnt,
    float* __restrict__ out) {
  // 32 m-tiles x 64 uint4 ([kh(2)][row(32)]) = 32 KB
  __shared__ __align__(16) uint4 afl[32 * 64];
  __shared__ float red[4];
  __shared__ int isLast;

  const int bid = blockIdx.x;          // 1024 = 32 db x 32 own-chunks
  const int tid = threadIdx.x;
  const int db  = bid >> 5;
  const int c   = bid & 31;
  const int dir = db >> 4, b = db & 15;
  const float* own   = (dir == 0 ? x : y) + (size_t)b * NPTS * 3;
  const float* other = (dir == 0 ? y : x) + (size_t)b * NPTS * 3;

  // ---- resident B-frag: 32 own pts per wave (1 n-tile) -------------------
  const int w = tid >> 6, l = tid & 63;
  const int col = l & 31, kh = l >> 5;
  const unsigned ONE = 0x3F80u;
  bf16x8 bfr;
  float sq;
  {
    const int n = c * CHUNK + w * 32 + col;
    float a0 = own[n * 3 + 0], a1 = own[n * 3 + 1], a2 = own[n * 3 + 2];
    sq = fmaf(a2, a2, fmaf(a1, a1, a0 * a0));        // exact f32, added last
    unsigned h0 = bf16rn(a0), h1 = bf16rn(a1), h2 = bf16rn(a2);
    unsigned e0 = bf16rn(a0 - bf2f(h0));
    unsigned e1 = bf16rn(a1 - bf2f(h1));
    unsigned e2 = bf16rn(a2 - bf2f(h2));
    union { unsigned uu[4]; bf16x8 v; } U;
    U.uu[0] = (kh == 0) ? pk(h0, h1) : pk(e2, ONE);
    U.uu[1] = (kh == 0) ? pk(h2, h0) : pk(ONE, 0u);
    U.uu[2] = (kh == 0) ? pk(h1, h2) : 0u;
    U.uu[3] = (kh == 0) ? pk(e0, e1) : 0u;
    bfr = U.v;
  }

  const int aoff = kh * 32 + col;      // lane's uint4 index within a tile
  const f32x16 z16 = {0.f, 0.f, 0.f, 0.f, 0.f, 0.f, 0.f, 0.f,
                      0.f, 0.f, 0.f, 0.f, 0.f, 0.f, 0.f, 0.f};
  float rm[8];
  #pragma unroll
  for (int j = 0; j < 8; ++j) rm[j] = 1e30f;

  // ---- 4 stages over the full other cloud -------------------------------
  for (int st = 0; st < NSTAGE; ++st) {
    __syncthreads();                   // prev compute done before overwrite
    const float* mp = other + (size_t)st * 1024 * 3;
    #pragma unroll
    for (int k = 0; k < 4; ++k) {
      const int p = tid + k * TPB;     // [0,1024)
      float y0 = mp[p * 3 + 0], y1 = mp[p * 3 + 1], y2 = mp[p * 3 + 2];
      float wv = fmaf(y2, y2, fmaf(y1, y1, y0 * y0));
      float z0 = -2.f * y0, z1 = -2.f * y1, z2 = -2.f * y2;
      unsigned h0 = bf16rn(z0), h1 = bf16rn(z1), h2 = bf16rn(z2);
      unsigned e0 = bf16rn(z0 - bf2f(h0));
      unsigned e1 = bf16rn(z1 - bf2f(h1));
      unsigned e2 = bf16rn(z2 - bf2f(h2));
      unsigned wh = bf16rn(wv), wl = bf16rn(wv - bf2f(wh));
      const int tile = p >> 5, row = p & 31;
      afl[tile * 64 + row]      =
          make_uint4(pk(h0, h1), pk(h2, e0), pk(e1, e2), pk(h0, h1)); // K0-7
      afl[tile * 64 + 32 + row] =
          make_uint4(pk(h2, wh), pk(wl, 0u), 0u, 0u);                 // K8-15
    }
    __syncthreads();

    #pragma unroll 4
    for (int mt = 0; mt < 32; ++mt) {
      union { uint4 u; bf16x8 v; } A;
      A.u = afl[mt * 64 + aoff];
      f32x16 acc = __builtin_amdgcn_mfma_f32_32x32x16_bf16(
          A.v, bfr, z16, 0, 0, 0);
      #pragma unroll
      for (int j = 0; j < 8; ++j)                    // 8x v_min3_f32
        rm[j] = fminf(fminf(acc[2 * j], acc[2 * j + 1]), rm[j]);
    }
  }

  // ---- epilogue: tree(8) once, fold lane^32 rows, add ||x||^2, wave sum --
  float v;
  {
    float t0 = fminf(fminf(rm[0], rm[1]), rm[2]);
    float t1 = fminf(fminf(rm[3], rm[4]), rm[5]);
    float t2 = fminf(rm[6], rm[7]);
    v = fminf(fminf(t0, t1), t2);
    v = fminf(v, __shfl_xor(v, 32, 64));             // rows in both kh halves
    v += sq;                                         // per-own-point min dist
  }
  // sum the wave's 32 own points (each col appears in lanes l and l+32)
  #pragma unroll
  for (int m = 1; m <= 16; m <<= 1) v += __shfl_xor(v, m, 64);
  if (l == 0) red[w] = v;
  __syncthreads();
  if (tid == 0)
    partials[bid] = (red[0] + red[1]) + (red[2] + red[3]);

  // ---- last-block finale (device counter, r6/r8-proven) ------------------
  if (tid == 0) {
    __threadfence();
    unsigned old = __hip_atomic_fetch_add(cnt, 1u, __ATOMIC_ACQ_REL,
                                          __HIP_MEMORY_SCOPE_AGENT);
    isLast = (old == NBLK - 1);
  }
  __syncthreads();
  if (isLast) {
    __threadfence();                                 // acquire side
    float* dls = (float*)afl;                        // reuse LDS
    if (tid < DB) {                                  // db = tid
      float s = 0.0f;
      #pragma unroll 8
      for (int j = 0; j < 32; ++j) {
        unsigned uv = __hip_atomic_load(
            (const unsigned*)&partials[tid * 32 + j], __ATOMIC_RELAXED,
            __HIP_MEMORY_SCOPE_AGENT);
        s += __uint_as_float(uv);
      }
      dls[tid] = s * (1.0f / (float)NPTS);
    }
    __syncthreads();
    if (tid < BATCH) {
      float mx = fmaxf(dls[tid], dls[tid + BATCH]);
      #pragma unroll
      for (int off = 8; off > 0; off >>= 1) mx += __shfl_down(mx, off, 16);
      if (tid == 0) out[0] = mx * (1.0f / (float)BATCH);
    }
  }
}

extern "C" void kernel_launch(void* const* d_in, const int* in_sizes, int n_in,
                              void* d_out, int out_size, void* d_ws, size_t ws_size,
                              hipStream_t stream) {
  const float* x = (const float*)d_in[0];
  const float* y = (const float*)d_in[1];
  float* out = (float*)d_out;

  float* partials = (float*)d_ws;                  // 1024 f32 = 4 KB
  unsigned* cnt   = (unsigned*)(partials + NBLK);  // 1 u32

  hipMemsetAsync(cnt, 0, 4, stream);               // graph-safe (r6-proven)
  chamfer_mm<<<NBLK, TPB, 0, stream>>>(x, y, partials, cnt, out);
}

// Round 17
// 30.393 us; speedup vs baseline: 1.8312x; 1.8312x over previous
//
#include <hip/hip_runtime.h>

// MaxChamferDistance: x[16,4096,3], y[16,4096,3] f32 -> scalar f32
//
// Round-17: r16 (self-sufficient blocks) regressed 2x from 4x-redundant
// staging + barrier/load serialization at 4 waves -- reverted. Its clean
// counters showed mm has no pipe >30% busy => per-wave dependent-latency
// chain (ds_read ~120cy single-outstanding -> MFMA latency -> min tree).
// This round = r12 verbatim (proven 29.8us, absmax 0) + THREE surgical
// latency breakers in the tile loop:
//  1. register double-buffer: prefetch A[mt+1] (wrap-index, no branch)
//     before issuing tile mt's MFMAs -> LDS latency hides under compute.
//  2. s_setprio(1) around the MFMA+min cluster (waves desynced post-barrier).
//  3. unroll 4 -> 4 prefetches in flight.
// Numerics/layout/combine unchanged (absmax 0 x6).

typedef __attribute__((ext_vector_type(8)))  short bf16x8;
typedef __attribute__((ext_vector_type(16))) float f32x16;

#define BATCH   16
#define NPTS    4096
#define DB      (2 * BATCH)            // 32 (dir,batch)
#define GM_F32  (2 * DB * NPTS)        // 262144 f32 = 1 MB

static __device__ __forceinline__ unsigned bf16rn(float f) {
  unsigned u = __float_as_uint(f);
  return (u + 0x7FFFu + ((u >> 16) & 1u)) >> 16;   // round-to-nearest-even
}
static __device__ __forceinline__ float bf2f(unsigned h) {
  return __uint_as_float(h << 16);
}
static __device__ __forceinline__ unsigned pk(unsigned lo, unsigned hi) {
  return (lo & 0xFFFFu) | (hi << 16);
}

__global__ __launch_bounds__(512, 4) void chamfer_mm(
    const float* __restrict__ x, const float* __restrict__ y,
    float* __restrict__ gm, unsigned* __restrict__ cnt) {
  // 64 m-tiles x 64 uint4 (tile layout: [kh(2)][row(32)]) = 64 KB
  __shared__ __align__(16) uint4 afl[64 * 64];

  const int bid = blockIdx.x;          // 512 = 32 db x 8 own-chunks x 2 halves
  const int tid = threadIdx.x;
  if (bid == 0 && tid == 0) *cnt = 0;  // combine's counter (stream-ordered)

  const int db  = bid >> 4;
  const int r   = bid & 15;
  const int c   = r >> 1;              // own chunk [0,8)
  const int h   = r & 1;               // m-half
  const int dir = db >> 4, b = db & 15;
  const float* own   = (dir == 0 ? x : y) + (size_t)b * NPTS * 3;
  const float* other = (dir == 0 ? y : x) + (size_t)b * NPTS * 3;
  const float* mp    = other + (size_t)h * 2048 * 3;

  // ---- stage: convert 2048 other pts -> A-frags in LDS (4 pts/thread) ----
  #pragma unroll
  for (int k = 0; k < 4; ++k) {
    const int p = tid + k * 512;       // [0,2048)
    float y0 = mp[p * 3 + 0], y1 = mp[p * 3 + 1], y2 = mp[p * 3 + 2];
    float wv = fmaf(y2, y2, fmaf(y1, y1, y0 * y0));
    float z0 = -2.f * y0, z1 = -2.f * y1, z2 = -2.f * y2;
    unsigned h0 = bf16rn(z0), h1 = bf16rn(z1), h2 = bf16rn(z2);
    unsigned e0 = bf16rn(z0 - bf2f(h0));
    unsigned e1 = bf16rn(z1 - bf2f(h1));
    unsigned e2 = bf16rn(z2 - bf2f(h2));
    unsigned wh = bf16rn(wv), wl = bf16rn(wv - bf2f(wh));
    const int tile = p >> 5, row = p & 31;
    afl[tile * 64 + row]      =
        make_uint4(pk(h0, h1), pk(h2, e0), pk(e1, e2), pk(h0, h1)); // K0-7
    afl[tile * 64 + 32 + row] =
        make_uint4(pk(h2, wh), pk(wl, 0u), 0u, 0u);                 // K8-15
  }

  // ---- resident B-frags: 64 own pts per wave (2 n-tiles of 32) ----------
  const int w = tid >> 6, l = tid & 63;
  const int col = l & 31, kh = l >> 5;
  const unsigned ONE = 0x3F80u;
  bf16x8 bfr[2];
  float sq[2], rmn[2];
  #pragma unroll
  for (int nt = 0; nt < 2; ++nt) {
    const int n = c * 512 + w * 64 + nt * 32 + col;
    float a0 = own[n * 3 + 0], a1 = own[n * 3 + 1], a2 = own[n * 3 + 2];
    sq[nt]  = fmaf(a2, a2, fmaf(a1, a1, a0 * a0));   // exact f32, added last
    rmn[nt] = 1e30f;
    unsigned h0 = bf16rn(a0), h1 = bf16rn(a1), h2 = bf16rn(a2);
    unsigned e0 = bf16rn(a0 - bf2f(h0));
    unsigned e1 = bf16rn(a1 - bf2f(h1));
    unsigned e2 = bf16rn(a2 - bf2f(h2));
    union { unsigned uu[4]; bf16x8 v; } U;
    U.uu[0] = (kh == 0) ? pk(h0, h1) : pk(e2, ONE);
    U.uu[1] = (kh == 0) ? pk(h2, h0) : pk(ONE, 0u);
    U.uu[2] = (kh == 0) ? pk(h1, h2) : 0u;
    U.uu[3] = (kh == 0) ? pk(e0, e1) : 0u;
    bfr[nt] = U.v;
  }
  __syncthreads();

  // ---- main loop: reg double-buffered A + setprio'd MFMA/min cluster ----
  const int aoff = kh * 32 + col;      // lane's uint4 index within a tile
  const f32x16 z16 = {0.f, 0.f, 0.f, 0.f, 0.f, 0.f, 0.f, 0.f,
                      0.f, 0.f, 0.f, 0.f, 0.f, 0.f, 0.f, 0.f};
  union { uint4 u; bf16x8 v; } Acur, Anxt;
  Acur.u = afl[aoff];                  // tile 0
  #pragma unroll 4
  for (int mt = 0; mt < 64; ++mt) {
    Anxt.u = afl[(((mt + 1) & 63) * 64) + aoff];     // prefetch (wraps)
    __builtin_amdgcn_s_setprio(1);
    #pragma unroll
    for (int nt = 0; nt < 2; ++nt) {
      f32x16 acc = __builtin_amdgcn_mfma_f32_32x32x16_bf16(
          Acur.v, bfr[nt], z16, 0, 0, 0);
      float m0 = fminf(fminf(acc[0],  acc[1]),  acc[2]);   // v_min3 chains
      float m1 = fminf(fminf(acc[3],  acc[4]),  acc[5]);
      float m2 = fminf(fminf(acc[6],  acc[7]),  acc[8]);
      float m3 = fminf(fminf(acc[9],  acc[10]), acc[11]);
      float m4 = fminf(fminf(acc[12], acc[13]), acc[14]);
      float m5 = fminf(fminf(acc[15], m0), m1);
      float m6 = fminf(fminf(m2, m3), m4);
      rmn[nt] = fminf(fminf(m5, m6), rmn[nt]);
    }
    __builtin_amdgcn_s_setprio(0);
    Acur = Anxt;
  }

  // ---- epilogue: rows live in both lane halves -> fold lane^32 ----------
  #pragma unroll
  for (int nt = 0; nt < 2; ++nt) {
    float v = fminf(rmn[nt], __shfl_xor(rmn[nt], 32, 64));
    float sv = v + sq[nt];
    if (l < 32)
      gm[(size_t)(h * DB + db) * NPTS + c * 512 + w * 64 + nt * 32 + col] = sv;
  }
}

// 32 blocks: min over halves + per-db mean; last block folds max/mean -> out.
__global__ __launch_bounds__(256) void chamfer_combine(
    const float* __restrict__ gm, float* __restrict__ dist,
    unsigned* __restrict__ cnt, float* __restrict__ out) {
  const int db = blockIdx.x;
  const float* g0 = gm + (size_t)db * NPTS;
  const float* g1 = gm + (size_t)(DB + db) * NPTS;
  float s = 0.0f;
  for (int i = threadIdx.x; i < NPTS; i += 256)
    s += fminf(g0[i], g1[i]);
  #pragma unroll
  for (int off = 32; off > 0; off >>= 1) s += __shfl_down(s, off, 64);
  __shared__ float red[4];
  const int lane = threadIdx.x & 63, wid = threadIdx.x >> 6;
  if (lane == 0) red[wid] = s;
  __syncthreads();
  if (threadIdx.x == 0) {
    dist[db] = ((red[0] + red[1]) + (red[2] + red[3])) * (1.0f / (float)NPTS);
    __threadfence();
    unsigned old = __hip_atomic_fetch_add(cnt, 1u, __ATOMIC_ACQ_REL,
                                          __HIP_MEMORY_SCOPE_AGENT);
    if (old == DB - 1) {
      __threadfence();
      float acc = 0.0f;
      #pragma unroll
      for (int b = 0; b < BATCH; ++b) {
        float d0 = __uint_as_float(__hip_atomic_load(
            (const unsigned*)&dist[b], __ATOMIC_RELAXED,
            __HIP_MEMORY_SCOPE_AGENT));
        float d1 = __uint_as_float(__hip_atomic_load(
            (const unsigned*)&dist[b + BATCH], __ATOMIC_RELAXED,
            __HIP_MEMORY_SCOPE_AGENT));
        acc += fmaxf(d0, d1);
      }
      out[0] = acc * (1.0f / (float)BATCH);
    }
  }
}

extern "C" void kernel_launch(void* const* d_in, const int* in_sizes, int n_in,
                              void* d_out, int out_size, void* d_ws, size_t ws_size,
                              hipStream_t stream) {
  const float* x = (const float*)d_in[0];
  const float* y = (const float*)d_in[1];
  float* out = (float*)d_out;

  float* gm     = (float*)d_ws;                    // 1 MB
  float* dist   = gm + GM_F32;                     // 32 f32
  unsigned* cnt = (unsigned*)(dist + DB);          // 1 u32

  chamfer_mm<<<512, 512, 0, stream>>>(x, y, gm, cnt);
  chamfer_combine<<<DB, 256, 0, stream>>>(gm, dist, cnt, out);
}